// Round 2
// baseline (462.828 us; speedup 1.0000x reference)
//
#include <hip/hip_runtime.h>

// Problem constants (fixed by reference)
#define BB 4
#define NN 4096
#define ROWS (BB*NN)     // 16384

typedef __attribute__((ext_vector_type(8))) short short8;
typedef __attribute__((ext_vector_type(4))) float f32x4;

__device__ __forceinline__ unsigned short f2bf(float f) {
    union { float f; unsigned int i; } cv; cv.f = f;
    unsigned int i = cv.i;
    return (unsigned short)((i + 0x7FFFu + ((i >> 16) & 1u)) >> 16);
}

// ---------------------------------------------------------------------------
// Kernel 1: fold weights -> WcatT bf16, B^T layout [n][k], n in [0,384):
//   n   0:128 -> Wu_top[k][n]; 128:256 -> (Wr@Wu_bot); 256:384 -> (Ws@Wu_bot)
// ---------------------------------------------------------------------------
__global__ __launch_bounds__(128) void fold_weights(const float* __restrict__ Wmsg,
                                                    const float* __restrict__ Wupd,
                                                    unsigned short* __restrict__ WcatT) {
    __shared__ float ldsS[128], ldsR[128];
    int k = blockIdx.x, t = threadIdx.x;
    ldsS[t] = Wmsg[k * 128 + t];            // Ws[k][t]
    ldsR[t] = Wmsg[(128 + k) * 128 + t];    // Wr[k][t]
    __syncthreads();
    float a1 = 0.f, a2 = 0.f;
#pragma unroll 8
    for (int m = 0; m < 128; ++m) {
        float wu = Wupd[(128 + m) * 128 + t];
        a1 += ldsS[m] * wu;
        a2 += ldsR[m] * wu;
    }
    WcatT[(size_t)t * 128 + k]         = f2bf(Wupd[k * 128 + t]);
    WcatT[(size_t)(128 + t) * 128 + k] = f2bf(a2);
    WcatT[(size_t)(256 + t) * 128 + k] = f2bf(a1);
}

// ---------------------------------------------------------------------------
// Kernel 2: MFMA GEMM: [T1|D2|YS] = x @ Wcat  (16384x128 @ 128x384, bf16 in, f32 acc)
// Block tile 64(M) x 128(N); 4 waves, wave = 16 rows x 128 cols (8 accum frags).
// nb==2 writes YS TRANSPOSED: YBT[b][n][s] bf16 (ys = x @ (Ws@Wu_bot)) so the
// SpMM can load B-fragments [n][k-contig] directly from global (L2-resident).
// ---------------------------------------------------------------------------
__global__ __launch_bounds__(256) void gemm_mfma(const float* __restrict__ X,
                                                 const unsigned short* __restrict__ WcatT,
                                                 float* __restrict__ TD,
                                                 unsigned short* __restrict__ YBT) {
    __shared__ unsigned short Al[64][136];    // [m][k], 272 B rows (16B-aligned)
    __shared__ unsigned short Bl[128][136];   // [n][k]
    int t  = threadIdx.x;
    int m0 = blockIdx.x * 64;
    int nb = blockIdx.y;          // 0,1,2

    // stage A: 64 rows x 128 k fp32 -> bf16. Thread: row m=t>>2, 32-float segment.
    {
        int m = t >> 2, seg = t & 3;
        const float* src = X + (size_t)(m0 + m) * 128 + seg * 32;
#pragma unroll
        for (int i = 0; i < 8; ++i) {
            float4 v = *(const float4*)(src + i * 4);
            ushort4 p;
            p.x = f2bf(v.x); p.y = f2bf(v.y); p.z = f2bf(v.z); p.w = f2bf(v.w);
            *(ushort4*)&Al[m][seg * 32 + i * 4] = p;
        }
    }
    // stage B: 128 rows x 128 k bf16 copy. Thread: row n=t>>1, 64-elem half = 8 x uint4.
    {
        int n = t >> 1, half = t & 1;
        const unsigned short* src = WcatT + (size_t)(nb * 128 + n) * 128 + half * 64;
#pragma unroll
        for (int i = 0; i < 8; ++i) {
            uint4 v = *(const uint4*)(src + i * 8);
            *(uint4*)&Bl[n][half * 64 + i * 8] = v;
        }
    }
    __syncthreads();

    int lane = t & 63, wave = t >> 6;
    int quad = lane >> 4, lr = lane & 15;
    int wm = wave * 16;
    f32x4 acc[8];
#pragma unroll
    for (int s = 0; s < 8; ++s) acc[s] = (f32x4)0.f;

#pragma unroll
    for (int kk = 0; kk < 4; ++kk) {
        short8 a = *(short8*)&Al[wm + lr][kk * 32 + quad * 8];
#pragma unroll
        for (int s = 0; s < 8; ++s) {
            short8 bf = *(short8*)&Bl[s * 16 + lr][kk * 32 + quad * 8];
            acc[s] = __builtin_amdgcn_mfma_f32_16x16x32_bf16(a, bf, acc[s], 0, 0, 0);
        }
    }

    // epilogue: C/D mapping col = lane&15, row = quad*4 + reg  [m89/m91]
    if (nb == 2) {
        // YBT[b][n][s]: b/s from global row (b constant per block since m0 % 64 == 0)
        int b = m0 >> 12;
        int s_base = (m0 & (NN - 1)) + wm + quad * 4;   // 4 consecutive source rows
#pragma unroll
        for (int s = 0; s < 8; ++s) {
            int n = s * 16 + lr;
            ushort4 p;
            p.x = f2bf(acc[s][0]); p.y = f2bf(acc[s][1]);
            p.z = f2bf(acc[s][2]); p.w = f2bf(acc[s][3]);
            *(ushort4*)&YBT[(((size_t)(b << 7) + n) << 12) + s_base] = p;
        }
    } else {
#pragma unroll
        for (int s = 0; s < 8; ++s)
#pragma unroll
            for (int r = 0; r < 4; ++r) {
                int row = m0 + wm + quad * 4 + r;
                TD[(size_t)row * 256 + nb * 128 + s * 16 + lr] = acc[s][r];
            }
    }
}

// ---------------------------------------------------------------------------
// Kernel 3: dense SpMM + epilogue:  out = T1 + (deg>0) * (D2 + (adj^T @ ys)/deg)
// adj is 1% dense but must be read in full regardless -> dense MFMA is
// BW-bound on adj (268 MB ~ 43 us floor) and replaces the entire sparse
// scan/bucket/gather pipeline. adj values {0,1} are exact in bf16; deg is
// accumulated exactly (f32 integer adds) during staging, for free.
// Block = 32 receivers x full K; K-tile 128. 512 blocks (2/CU, 8 waves/CU).
// A-tile staged via registers (coalesced 4B/lane column reads + f2bf) into
// LDS [r][k]; B-frags (ys) read directly from global YBT (L2, 1 MB/batch).
// ---------------------------------------------------------------------------
#define RT 32        // receiver tile
#define KT 128       // k tile
#define NT (NN/KT)   // 32 iterations
__global__ __launch_bounds__(256) void spmm_out(const float* __restrict__ adj,
                                                const unsigned short* __restrict__ YBT,
                                                const float* __restrict__ TD,
                                                float* __restrict__ out) {
    __shared__ unsigned short At[RT][KT + 8];   // [32][136] bf16, 272 B rows
    __shared__ float degp[8][RT];
    __shared__ float deg_s[RT];

    int t  = threadIdx.x;
    int r0 = blockIdx.x * RT;     // 128 r-tiles
    int b  = blockIdx.y;          // 4 batches
    const float* adj_b = adj + (size_t)b * NN * NN;

    int r  = t & 31;              // staging: receiver column owned by thread
    int kg = t >> 5;              // 0..7, each 16 consecutive k (source rows)
    float va[16];                 // reg-staged adj column slice (const-indexed)
    float dpart = 0.f;

    int lane = t & 63, wave = t >> 6;
    int wr = wave & 1, wn = wave >> 1;      // wave: 16 r x 64 n quadrant
    int quad = lane >> 4, lr = lane & 15;
    const unsigned short* ybt = YBT + ((size_t)b << 19);   // b*128*4096

    f32x4 acc0 = (f32x4)0.f, acc1 = (f32x4)0.f, acc2 = (f32x4)0.f, acc3 = (f32x4)0.f;

    // prologue: issue loads for tile 0 (16 coalesced 4B column reads)
    {
        const float* p = adj_b + (size_t)(kg * 16) * NN + r0 + r;
#pragma unroll
        for (int j = 0; j < 16; ++j) va[j] = p[(size_t)j * NN];
    }

    for (int tt = 0; tt < NT; ++tt) {
        __syncthreads();          // readers of tile tt-1 done; drains va loads
        // write phase: f32 -> bf16, deg accumulation (adj values are 0/1)
        short8 w0, w1;
#pragma unroll
        for (int j = 0; j < 8; ++j) {
            w0[j] = (short)f2bf(va[j]);
            w1[j] = (short)f2bf(va[j + 8]);
            dpart += va[j] + va[j + 8];
        }
        *(short8*)&At[r][kg * 16]     = w0;
        *(short8*)&At[r][kg * 16 + 8] = w1;
        __syncthreads();          // tile tt visible
        // issue next tile's loads (in flight across MFMA phase)
        if (tt + 1 < NT) {
            const float* p = adj_b + (size_t)((tt + 1) * KT + kg * 16) * NN + r0 + r;
#pragma unroll
            for (int j = 0; j < 16; ++j) va[j] = p[(size_t)j * NN];
        }
        // MFMA phase: A from LDS, B direct from global (L2-resident YBT)
        int k0 = tt * KT;
#pragma unroll
        for (int kk = 0; kk < 4; ++kk) {
            short8 a = *(short8*)&At[wr * 16 + lr][kk * 32 + quad * 8];
            const unsigned short* bp = ybt + (((size_t)(wn * 64 + lr)) << 12) + k0 + kk * 32 + quad * 8;
            short8 b0 = *(const short8*)(bp);
            short8 b1 = *(const short8*)(bp + (16 << 12));
            short8 b2 = *(const short8*)(bp + (32 << 12));
            short8 b3 = *(const short8*)(bp + (48 << 12));
            acc0 = __builtin_amdgcn_mfma_f32_16x16x32_bf16(a, b0, acc0, 0, 0, 0);
            acc1 = __builtin_amdgcn_mfma_f32_16x16x32_bf16(a, b1, acc1, 0, 0, 0);
            acc2 = __builtin_amdgcn_mfma_f32_16x16x32_bf16(a, b2, acc2, 0, 0, 0);
            acc3 = __builtin_amdgcn_mfma_f32_16x16x32_bf16(a, b3, acc3, 0, 0, 0);
        }
    }

    // exact degree reduce: thread's slice covered k = {tt*128 + kg*16 + j}
    __syncthreads();
    degp[kg][r] = dpart;
    __syncthreads();
    if (t < RT) {
        float s = 0.f;
#pragma unroll
        for (int g = 0; g < 8; ++g) s += degp[g][t];
        deg_s[t] = s;
    }
    __syncthreads();

    // epilogue: out = T1 + (deg>0) * (D2 + acc/deg)
    const float* td = TD + ((size_t)(b * NN + r0)) * 256;
    float* ob = out + ((size_t)(b * NN + r0)) * 128;
#pragma unroll
    for (int sf = 0; sf < 4; ++sf) {
        f32x4 a = (sf == 0) ? acc0 : (sf == 1) ? acc1 : (sf == 2) ? acc2 : acc3;
        int n = wn * 64 + sf * 16 + lr;
#pragma unroll
        for (int rr = 0; rr < 4; ++rr) {
            int rl = wr * 16 + quad * 4 + rr;
            float deg = deg_s[rl];
            float v = td[(size_t)rl * 256 + n];
            if (deg > 0.f)
                v += td[(size_t)rl * 256 + 128 + n] + a[rr] / deg;
            ob[(size_t)rl * 128 + n] = v;
        }
    }
}

// ---------------------------------------------------------------------------
extern "C" void kernel_launch(void* const* d_in, const int* in_sizes, int n_in,
                              void* d_out, int out_size, void* d_ws, size_t ws_size,
                              hipStream_t stream) {
    const float* x    = (const float*)d_in[0];   // 16384 x 128
    const float* adj  = (const float*)d_in[1];   // 4 x 4096 x 4096
    const float* Wmsg = (const float*)d_in[2];   // 256 x 128
    const float* Wupd = (const float*)d_in[3];   // 256 x 128
    float* out = (float*)d_out;                  // 16384 x 128

    // workspace layout (bytes, 256-aligned); total ~20.1 MB
    char* ws = (char*)d_ws;
    unsigned short* WcatT = (unsigned short*)(ws);                     // 96 KB used (128 KB reserved)
    float*          TD    = (float*)(ws + 131072);                     // 16 MB (T1|D2 per row)
    unsigned short* YBT   = (unsigned short*)(ws + 131072 + 16777216); // 4 MB, [b][n=128][s=4096] bf16

    fold_weights<<<128, 128, 0, stream>>>(Wmsg, Wupd, WcatT);
    gemm_mfma<<<dim3(256, 3), 256, 0, stream>>>(x, WcatT, TD, YBT);
    spmm_out<<<dim3(NN / RT, BB), 256, 0, stream>>>(adj, YBT, TD, out);
}